// Round 1
// baseline (1017.500 us; speedup 1.0000x reference)
//
#include <hip/hip_runtime.h>
#include <math.h>

#define B_ROWS 16384
#define DK     512
#define NK     4096
#define DV     512
#define H_MLP  32

typedef __attribute__((ext_vector_type(8))) short s16x8;
typedef __attribute__((ext_vector_type(4))) short s16x4;
typedef __attribute__((ext_vector_type(4))) float f32x4;

__device__ __forceinline__ short f2bf(float f) {
  unsigned u = __float_as_uint(f);
  u += 0x7fffu + ((u >> 16) & 1u);   // round-to-nearest-even
  return (short)(u >> 16);
}

// ---------------------------------------------------------------------------
// K0: transpose values [NK x DV] fp32 -> vT [DV x NK] bf16
// ---------------------------------------------------------------------------
__global__ __launch_bounds__(256) void transpose_v(const float* __restrict__ v,
                                                   short* __restrict__ vT) {
  __shared__ float tile[32][33];
  const int tx = threadIdx.x & 31;
  const int ty = threadIdx.x >> 5;           // 0..7
  const int k0 = blockIdx.x * 32;            // over NK
  const int n0 = blockIdx.y * 32;            // over DV
#pragma unroll
  for (int j = 0; j < 4; ++j)
    tile[ty + j * 8][tx] = v[(long)(k0 + ty + j * 8) * DV + n0 + tx];
  __syncthreads();
#pragma unroll
  for (int j = 0; j < 4; ++j)
    vT[(long)(n0 + ty + j * 8) * NK + k0 + tx] = f2bf(tile[tx][ty + j * 8]);
}

// ---------------------------------------------------------------------------
// Staging helpers: global -> LDS tile [128 rows][64 k] bf16
// ---------------------------------------------------------------------------
__device__ __forceinline__ void stage_f32(const float* __restrict__ src, int ldk,
                                          int row0, int k0, short* lds, int tid) {
#pragma unroll
  for (int i = 0; i < 8; ++i) {
    int f   = i * 256 + tid;
    int row = f >> 4;
    int c4  = (f & 15) * 4;
    float4 v = *(const float4*)(src + (long)(row0 + row) * ldk + k0 + c4);
    s16x4 s;
    s.x = f2bf(v.x); s.y = f2bf(v.y); s.z = f2bf(v.z); s.w = f2bf(v.w);
    *(s16x4*)(lds + row * 64 + c4) = s;
  }
}

__device__ __forceinline__ void stage_bf(const short* __restrict__ src, int ldk,
                                         int row0, int k0, short* lds, int tid) {
#pragma unroll
  for (int i = 0; i < 4; ++i) {
    int f   = i * 256 + tid;
    int row = f >> 3;
    int c8  = (f & 7) * 8;
    s16x8 v = *(const s16x8*)(src + (long)(row0 + row) * ldk + k0 + c8);
    *(s16x8*)(lds + row * 64 + c8) = v;
  }
}

// ---------------------------------------------------------------------------
// NT GEMM: C[M x N] = alpha * A[M x K] * B[N x K]^T
// A fp32, B fp32 or bf16 (BBF). bf16 MFMA 16x16x32, 128x128 tile, BK=64.
// ---------------------------------------------------------------------------
template <bool BBF>
__global__ __launch_bounds__(256) void gemm_nt(const float* __restrict__ A,
                                               const void* __restrict__ Bv,
                                               float* __restrict__ C,
                                               int M, int N, int K, float alpha) {
  __shared__ short As[128 * 64];
  __shared__ short Bs[128 * 64];
  const int tid     = threadIdx.x;
  const int rowBase = blockIdx.y * 128;
  const int colBase = blockIdx.x * 128;
  const int wid  = tid >> 6, lane = tid & 63;
  const int waveM = wid >> 1, waveN = wid & 1;
  const int quad = lane >> 4, lr = lane & 15;

  f32x4 acc[4][4];
#pragma unroll
  for (int i = 0; i < 4; ++i)
#pragma unroll
    for (int j = 0; j < 4; ++j)
      acc[i][j] = (f32x4){0.f, 0.f, 0.f, 0.f};

  for (int k0 = 0; k0 < K; k0 += 64) {
    __syncthreads();
    stage_f32(A, K, rowBase, k0, As, tid);
    if constexpr (BBF)
      stage_bf((const short*)Bv, K, colBase, k0, Bs, tid);
    else
      stage_f32((const float*)Bv, K, colBase, k0, Bs, tid);
    __syncthreads();
#pragma unroll
    for (int ks = 0; ks < 2; ++ks) {
      s16x8 a[4], b[4];
#pragma unroll
      for (int t = 0; t < 4; ++t) {
        a[t] = *(const s16x8*)(As + (waveM * 64 + t * 16 + lr) * 64 + ks * 32 + quad * 8);
        b[t] = *(const s16x8*)(Bs + (waveN * 64 + t * 16 + lr) * 64 + ks * 32 + quad * 8);
      }
#pragma unroll
      for (int mt = 0; mt < 4; ++mt)
#pragma unroll
        for (int nt = 0; nt < 4; ++nt)
          acc[mt][nt] = __builtin_amdgcn_mfma_f32_16x16x32_bf16(a[mt], b[nt], acc[mt][nt], 0, 0, 0);
    }
  }

#pragma unroll
  for (int mt = 0; mt < 4; ++mt)
#pragma unroll
    for (int nt = 0; nt < 4; ++nt) {
      int col = colBase + waveN * 64 + nt * 16 + lr;
#pragma unroll
      for (int r = 0; r < 4; ++r) {
        int row = rowBase + waveM * 64 + mt * 16 + quad * 4 + r;
        C[(long)row * N + col] = acc[mt][nt][r] * alpha;
      }
    }
}

// ---------------------------------------------------------------------------
// K2: per-row max / Z / E1 -> entropy -> MLP -> tau. One wave per row.
// ---------------------------------------------------------------------------
__global__ __launch_bounds__(256) void row_entropy_tau(
    const float* __restrict__ l, float* __restrict__ ent_out,
    float* __restrict__ tau_out, float* __restrict__ m_arr,
    float* __restrict__ tauE_arr, const float* __restrict__ w1,
    const float* __restrict__ b1, const float* __restrict__ w2,
    const float* __restrict__ b2) {
  const int wid = threadIdx.x >> 6, lane = threadIdx.x & 63;
  const int row = blockIdx.x * 4 + wid;
  const float4* lr = (const float4*)(l + (long)row * NK);

  float m = -3.4e38f;
#pragma unroll
  for (int it = 0; it < 16; ++it) {
    float4 v = lr[it * 64 + lane];
    m = fmaxf(m, fmaxf(fmaxf(v.x, v.y), fmaxf(v.z, v.w)));
  }
#pragma unroll
  for (int off = 32; off >= 1; off >>= 1) m = fmaxf(m, __shfl_xor(m, off));

  float Z = 0.f, E1 = 0.f;
#pragma unroll
  for (int it = 0; it < 16; ++it) {
    float4 v = lr[it * 64 + lane];
    float e0 = expf(v.x - m), e1 = expf(v.y - m);
    float e2 = expf(v.z - m), e3 = expf(v.w - m);
    Z  += (e0 + e1) + (e2 + e3);
    E1 += v.x * e0 + v.y * e1 + v.z * e2 + v.w * e3;
  }
#pragma unroll
  for (int off = 32; off >= 1; off >>= 1) {
    Z  += __shfl_xor(Z, off);
    E1 += __shfl_xor(E1, off);
  }

  float entropy = m + logf(Z) - E1 / Z;            // -sum p log p (eps term negligible)
  float en = entropy / 8.3177662f;                  // / log(4096)
  en = fminf(fmaxf(en, 0.f), 1.f);

  float hp = 0.f;
  if (lane < H_MLP) {
    float x = en * w1[lane] + b1[lane];
    float g = 0.5f * x * (1.f + erff(x * 0.70710678f));   // exact GELU
    hp = g * w2[lane];
  }
#pragma unroll
  for (int off = 16; off >= 1; off >>= 1) hp += __shfl_xor(hp, off);

  if (lane == 0) {
    float s   = 1.f / (1.f + expf(-(hp + b2[0])));
    float tau = 0.1f + 4.9f * s;
    ent_out[row]  = en;
    tau_out[row]  = tau;
    m_arr[row]    = m;
    tauE_arr[row] = tau + 1e-8f;
  }
}

// ---------------------------------------------------------------------------
// K3: in-place softmax over l with temperature. One wave per row.
// ---------------------------------------------------------------------------
__global__ __launch_bounds__(256) void attn_softmax(float* __restrict__ l,
                                                    const float* __restrict__ m_arr,
                                                    const float* __restrict__ tauE_arr) {
  const int wid = threadIdx.x >> 6, lane = threadIdx.x & 63;
  const int row = blockIdx.x * 4 + wid;
  float4* lr = (float4*)(l + (long)row * NK);
  const float m    = m_arr[row];
  const float itau = 1.f / tauE_arr[row];

  float Z = 0.f;
#pragma unroll
  for (int it = 0; it < 16; ++it) {
    float4 v = lr[it * 64 + lane];
    Z += expf((v.x - m) * itau) + expf((v.y - m) * itau) +
         expf((v.z - m) * itau) + expf((v.w - m) * itau);
  }
#pragma unroll
  for (int off = 32; off >= 1; off >>= 1) Z += __shfl_xor(Z, off);
  const float inv = 1.f / Z;

#pragma unroll
  for (int it = 0; it < 16; ++it) {
    float4 v = lr[it * 64 + lane];
    v.x = expf((v.x - m) * itau) * inv;
    v.y = expf((v.y - m) * itau) * inv;
    v.z = expf((v.z - m) * itau) * inv;
    v.w = expf((v.w - m) * itau) * inv;
    lr[it * 64 + lane] = v;
  }
}

// ---------------------------------------------------------------------------
extern "C" void kernel_launch(void* const* d_in, const int* in_sizes, int n_in,
                              void* d_out, int out_size, void* d_ws, size_t ws_size,
                              hipStream_t stream) {
  const float* q    = (const float*)d_in[0];
  const float* keys = (const float*)d_in[1];
  const float* vals = (const float*)d_in[2];
  const float* w1   = (const float*)d_in[3];
  const float* b1   = (const float*)d_in[4];
  const float* w2   = (const float*)d_in[5];
  const float* b2   = (const float*)d_in[6];

  float* out  = (float*)d_out;                 // [B, DV]
  float* attn = out + (long)B_ROWS * DV;       // [B, NK]  (holds l, then attn)
  float* ent  = attn + (long)B_ROWS * NK;      // [B, 1]
  float* tau  = ent + B_ROWS;                  // [B, 1]

  short* vT       = (short*)d_ws;                                       // [DV, NK] bf16
  float* m_arr    = (float*)((char*)d_ws + (size_t)DV * NK * sizeof(short));
  float* tauE_arr = m_arr + B_ROWS;

  const float base_scale = 0.044194173824159216f;  // 512^-0.5

  transpose_v<<<dim3(NK / 32, DV / 32), 256, 0, stream>>>(vals, vT);
  gemm_nt<false><<<dim3(NK / 128, B_ROWS / 128), 256, 0, stream>>>(
      q, keys, attn, B_ROWS, NK, DK, base_scale);
  row_entropy_tau<<<B_ROWS / 4, 256, 0, stream>>>(attn, ent, tau, m_arr, tauE_arr,
                                                  w1, b1, w2, b2);
  attn_softmax<<<B_ROWS / 4, 256, 0, stream>>>(attn, m_arr, tauE_arr);
  gemm_nt<true><<<dim3(DV / 128, B_ROWS / 128), 256, 0, stream>>>(
      attn, vT, out, B_ROWS, DV, NK, 1.0f);
}

// Round 2
// 687.579 us; speedup vs baseline: 1.4798x; 1.4798x over previous
//
#include <hip/hip_runtime.h>
#include <math.h>

#define B_ROWS 16384
#define DK     512
#define NK     4096
#define DV     512
#define H_MLP  32

typedef __attribute__((ext_vector_type(8))) short s16x8;
typedef __attribute__((ext_vector_type(4))) short s16x4;
typedef __attribute__((ext_vector_type(4))) float f32x4;

__device__ __forceinline__ short f2bf(float f) {
  unsigned u = __float_as_uint(f);
  u += 0x7fffu + ((u >> 16) & 1u);   // round-to-nearest-even
  return (short)(u >> 16);
}

__device__ __forceinline__ void async_cp16(const short* g, short* l) {
  __builtin_amdgcn_global_load_lds(
      (const __attribute__((address_space(1))) unsigned int*)g,
      (__attribute__((address_space(3))) unsigned int*)l, 16, 0, 0);
}

// ---------------------------------------------------------------------------
// fp32 -> bf16 convert (optional scale). n multiple of 2048.
// ---------------------------------------------------------------------------
__global__ __launch_bounds__(256) void cvt_bf16(const float* __restrict__ src,
                                                short* __restrict__ dst,
                                                long n, float scale) {
  long i = ((long)blockIdx.x * 256 + threadIdx.x) * 8;
  if (i >= n) return;
  float4 a = *(const float4*)(src + i);
  float4 b = *(const float4*)(src + i + 4);
  s16x8 o;
  o[0] = f2bf(a.x * scale); o[1] = f2bf(a.y * scale);
  o[2] = f2bf(a.z * scale); o[3] = f2bf(a.w * scale);
  o[4] = f2bf(b.x * scale); o[5] = f2bf(b.y * scale);
  o[6] = f2bf(b.z * scale); o[7] = f2bf(b.w * scale);
  *(s16x8*)(dst + i) = o;
}

// ---------------------------------------------------------------------------
// transpose values [NK x DV] fp32 -> vT [DV x NK] bf16
// ---------------------------------------------------------------------------
__global__ __launch_bounds__(256) void transpose_v(const float* __restrict__ v,
                                                   short* __restrict__ vT) {
  __shared__ float tile[32][33];
  const int tx = threadIdx.x & 31;
  const int ty = threadIdx.x >> 5;
  const int k0 = blockIdx.x * 32;   // over NK
  const int n0 = blockIdx.y * 32;   // over DV
#pragma unroll
  for (int j = 0; j < 4; ++j)
    tile[ty + j * 8][tx] = v[(long)(k0 + ty + j * 8) * DV + n0 + tx];
  __syncthreads();
#pragma unroll
  for (int j = 0; j < 4; ++j)
    vT[(long)(n0 + ty + j * 8) * NK + k0 + tx] = f2bf(tile[tx][ty + j * 8]);
}

// ---------------------------------------------------------------------------
// Staging: global -> LDS tile [128 rows][64 k] bf16, XOR-swizzled chunks.
// LDS slot (row, pos p in 0..7, 8 shorts/chunk) holds global chunk p^(row&7).
// ---------------------------------------------------------------------------
__device__ __forceinline__ void stage_f32_sw(const float* __restrict__ src, int ldk,
                                             int row0, int k0, short* lds, int tid) {
#pragma unroll
  for (int i = 0; i < 4; ++i) {
    int f   = i * 256 + tid;     // 0..1023
    int row = f >> 3;
    int p   = f & 7;
    int c   = p ^ (row & 7);
    const float* gp = src + (long)(row0 + row) * ldk + k0 + c * 8;
    float4 a = *(const float4*)gp;
    float4 b = *(const float4*)(gp + 4);
    s16x8 o;
    o[0] = f2bf(a.x); o[1] = f2bf(a.y); o[2] = f2bf(a.z); o[3] = f2bf(a.w);
    o[4] = f2bf(b.x); o[5] = f2bf(b.y); o[6] = f2bf(b.z); o[7] = f2bf(b.w);
    *(s16x8*)(lds + row * 64 + p * 8) = o;
  }
}

// async: wave w stages rows [w*32, w*32+32). Lane's LDS dest = base + lane*16B.
__device__ __forceinline__ void stage_bf_async(const short* __restrict__ src, int ldk,
                                               int row0, int k0, short* lds,
                                               int w, int lane) {
  const int srow = lane >> 3;              // 0..7
  const int c    = (lane & 7) ^ srow;      // swizzled source chunk
  const short* g = src + (long)(row0 + w * 32 + srow) * ldk + k0 + c * 8;
  short* lb = lds + w * 2048;              // wave-uniform
#pragma unroll
  for (int i = 0; i < 4; ++i)
    async_cp16(g + (long)(i * 8) * ldk, lb + i * 512);
}

// ---------------------------------------------------------------------------
// NT GEMM: C[M x N] = alpha * A[M x K] * B[N x K]^T, bf16 MFMA 16x16x32,
// 128x128 tile, BK=64. MODE 1 = bf16 source via global_load_lds, 0 = fp32+cvt.
// ---------------------------------------------------------------------------
template <int AMODE, int BMODE>
__global__ __launch_bounds__(256) void gemm_nt(const void* __restrict__ Av,
                                               const void* __restrict__ Bv,
                                               float* __restrict__ C,
                                               int M, int N, int K, float alpha) {
  __shared__ short As[128 * 64];
  __shared__ short Bs[128 * 64];
  const int tid     = threadIdx.x;
  const int rowBase = blockIdx.y * 128;
  const int colBase = blockIdx.x * 128;
  const int w = tid >> 6, lane = tid & 63;
  const int waveM = w >> 1, waveN = w & 1;
  const int quad = lane >> 4, lr = lane & 15;
  const int sw = lr & 7;

  f32x4 acc[4][4];
#pragma unroll
  for (int i = 0; i < 4; ++i)
#pragma unroll
    for (int j = 0; j < 4; ++j)
      acc[i][j] = (f32x4){0.f, 0.f, 0.f, 0.f};

  for (int k0 = 0; k0 < K; k0 += 64) {
    __syncthreads();
    if constexpr (AMODE)
      stage_bf_async((const short*)Av, K, rowBase, k0, As, w, lane);
    else
      stage_f32_sw((const float*)Av, K, rowBase, k0, As, tid);
    if constexpr (BMODE)
      stage_bf_async((const short*)Bv, K, colBase, k0, Bs, w, lane);
    else
      stage_f32_sw((const float*)Bv, K, colBase, k0, Bs, tid);
    __syncthreads();
#pragma unroll
    for (int ks = 0; ks < 2; ++ks) {
      const int cpos = ((ks * 4 + quad) ^ sw) * 8;
      s16x8 a[4], b[4];
#pragma unroll
      for (int t = 0; t < 4; ++t) {
        a[t] = *(const s16x8*)(As + (waveM * 64 + t * 16 + lr) * 64 + cpos);
        b[t] = *(const s16x8*)(Bs + (waveN * 64 + t * 16 + lr) * 64 + cpos);
      }
#pragma unroll
      for (int mt = 0; mt < 4; ++mt)
#pragma unroll
        for (int nt = 0; nt < 4; ++nt)
          acc[mt][nt] = __builtin_amdgcn_mfma_f32_16x16x32_bf16(a[mt], b[nt], acc[mt][nt], 0, 0, 0);
    }
  }

#pragma unroll
  for (int mt = 0; mt < 4; ++mt)
#pragma unroll
    for (int nt = 0; nt < 4; ++nt) {
      int col = colBase + waveN * 64 + nt * 16 + lr;
#pragma unroll
      for (int r = 0; r < 4; ++r) {
        int row = rowBase + waveM * 64 + mt * 16 + quad * 4 + r;
        C[(long)row * N + col] = acc[mt][nt][r] * alpha;
      }
    }
}

// ---------------------------------------------------------------------------
// Fused: per-row stats -> entropy -> MLP -> tau -> softmax write (fp32 + opt
// bf16 copy). One wave per row; l normalized in place.
// ---------------------------------------------------------------------------
__global__ __launch_bounds__(256) void entropy_softmax(
    float* __restrict__ l, short* __restrict__ attn_bf,
    float* __restrict__ ent_out, float* __restrict__ tau_out,
    const float* __restrict__ w1, const float* __restrict__ b1,
    const float* __restrict__ w2, const float* __restrict__ b2) {
  const int wid = threadIdx.x >> 6, lane = threadIdx.x & 63;
  const int row = blockIdx.x * 4 + wid;
  float4* lr = (float4*)(l + (long)row * NK);

  // pass 1: max, Z, E1 at base scale
  float m = -3.4e38f;
#pragma unroll
  for (int it = 0; it < 16; ++it) {
    float4 v = lr[it * 64 + lane];
    m = fmaxf(m, fmaxf(fmaxf(v.x, v.y), fmaxf(v.z, v.w)));
  }
#pragma unroll
  for (int off = 32; off >= 1; off >>= 1) m = fmaxf(m, __shfl_xor(m, off));

  float Z = 0.f, E1 = 0.f;
#pragma unroll
  for (int it = 0; it < 16; ++it) {
    float4 v = lr[it * 64 + lane];
    float e0 = expf(v.x - m), e1 = expf(v.y - m);
    float e2 = expf(v.z - m), e3 = expf(v.w - m);
    Z  += (e0 + e1) + (e2 + e3);
    E1 += v.x * e0 + v.y * e1 + v.z * e2 + v.w * e3;
  }
#pragma unroll
  for (int off = 32; off >= 1; off >>= 1) {
    Z  += __shfl_xor(Z, off);
    E1 += __shfl_xor(E1, off);
  }

  float entropy = m + logf(Z) - E1 / Z;
  float en = fminf(fmaxf(entropy / 8.3177662f, 0.f), 1.f);  // / log(4096)

  float hp = 0.f;
  if (lane < H_MLP) {
    float x = en * w1[lane] + b1[lane];
    float g = 0.5f * x * (1.f + erff(x * 0.70710678f));     // exact GELU
    hp = g * w2[lane];
  }
#pragma unroll
  for (int off = 16; off >= 1; off >>= 1) hp += __shfl_xor(hp, off);
  hp = __shfl(hp, 0);

  float s    = 1.f / (1.f + expf(-(hp + b2[0])));
  float tau  = 0.1f + 4.9f * s;
  float itau = 1.f / (tau + 1e-8f);
  if (lane == 0) { ent_out[row] = en; tau_out[row] = tau; }

  // pass 2: Z at temperature tau
  float Z2 = 0.f;
#pragma unroll
  for (int it = 0; it < 16; ++it) {
    float4 v = lr[it * 64 + lane];
    Z2 += expf((v.x - m) * itau) + expf((v.y - m) * itau) +
          expf((v.z - m) * itau) + expf((v.w - m) * itau);
  }
#pragma unroll
  for (int off = 32; off >= 1; off >>= 1) Z2 += __shfl_xor(Z2, off);
  const float inv = 1.f / Z2;

  // pass 3: write normalized fp32 (+ bf16 copy)
  short* br = attn_bf ? attn_bf + (long)row * NK : nullptr;
#pragma unroll
  for (int it = 0; it < 16; ++it) {
    float4 v = lr[it * 64 + lane];
    v.x = expf((v.x - m) * itau) * inv;
    v.y = expf((v.y - m) * itau) * inv;
    v.z = expf((v.z - m) * itau) * inv;
    v.w = expf((v.w - m) * itau) * inv;
    lr[it * 64 + lane] = v;
    if (br) {
      s16x4 o;
      o.x = f2bf(v.x); o.y = f2bf(v.y); o.z = f2bf(v.z); o.w = f2bf(v.w);
      *(s16x4*)(br + (it * 64 + lane) * 4) = o;
    }
  }
}

// ---------------------------------------------------------------------------
extern "C" void kernel_launch(void* const* d_in, const int* in_sizes, int n_in,
                              void* d_out, int out_size, void* d_ws, size_t ws_size,
                              hipStream_t stream) {
  const float* q    = (const float*)d_in[0];
  const float* keys = (const float*)d_in[1];
  const float* vals = (const float*)d_in[2];
  const float* w1   = (const float*)d_in[3];
  const float* b1   = (const float*)d_in[4];
  const float* w2   = (const float*)d_in[5];
  const float* b2   = (const float*)d_in[6];

  float* out  = (float*)d_out;                 // [B, DV]
  float* attn = out + (long)B_ROWS * DV;       // [B, NK]  (l -> attn, in place)
  float* ent  = attn + (long)B_ROWS * NK;      // [B, 1]
  float* tau  = ent + B_ROWS;                  // [B, 1]

  char* ws = (char*)d_ws;
  const size_t off_vT    = 0;
  const size_t off_keysb = off_vT + (size_t)DV * NK * 2;
  const size_t off_qb    = off_keysb + (size_t)NK * DK * 2;
  const size_t off_attnb = off_qb + (size_t)B_ROWS * DK * 2;
  const size_t need_mid  = off_attnb;                              // ~24 MB
  const size_t need_full = off_attnb + (size_t)B_ROWS * NK * 2;    // ~158 MB

  short* vT    = (short*)(ws + off_vT);
  short* keysb = (short*)(ws + off_keysb);
  short* qb    = (short*)(ws + off_qb);
  short* attnb = (short*)(ws + off_attnb);

  const float base_scale = 0.044194173824159216f;  // 512^-0.5

  transpose_v<<<dim3(NK / 32, DV / 32), 256, 0, stream>>>(vals, vT);

  if (ws_size >= need_mid) {
    // bf16 operand prep (scale folded into q)
    cvt_bf16<<<(int)(((long)B_ROWS * DK) / 2048), 256, 0, stream>>>(
        q, qb, (long)B_ROWS * DK, base_scale);
    cvt_bf16<<<(int)(((long)NK * DK) / 2048), 256, 0, stream>>>(
        keys, keysb, (long)NK * DK, 1.0f);
    gemm_nt<1, 1><<<dim3(NK / 128, B_ROWS / 128), 256, 0, stream>>>(
        qb, keysb, attn, B_ROWS, NK, DK, 1.0f);
  } else {
    gemm_nt<0, 0><<<dim3(NK / 128, B_ROWS / 128), 256, 0, stream>>>(
        q, keys, attn, B_ROWS, NK, DK, base_scale);
  }

  const bool full = ws_size >= need_full;
  entropy_softmax<<<B_ROWS / 4, 256, 0, stream>>>(
      attn, full ? attnb : nullptr, ent, tau, w1, b1, w2, b2);

  if (full)
    gemm_nt<1, 1><<<dim3(DV / 128, B_ROWS / 128), 256, 0, stream>>>(
        attnb, vT, out, B_ROWS, DV, NK, 1.0f);
  else
    gemm_nt<0, 1><<<dim3(DV / 128, B_ROWS / 128), 256, 0, stream>>>(
        attn, vT, out, B_ROWS, DV, NK, 1.0f);
}